// Round 11
// baseline (302.571 us; speedup 1.0000x reference)
//
#include <hip/hip_runtime.h>
#include <hip/hip_bf16.h>

// PartiallyExchangeableNetwork on MI355X (gfx950)
// N=256, M=3, T=4096, ORDER=2 -> L=4094 windows, H=128, OUT=10
//
// h1 = relu(xin @ W1 + b1); h2 = relu(h1 @ W2 + b2); colsum over L.
// Layer 3 folded through the sum: sum_l(h2@W3+b3) = (sum_l h2)@W3 + L*b3 (tail).
//
// R11: 2x2 wave grid + register handoff + LDS mailbox.
// Wave (wr,wc) owns rows [32wr,32wr+32) x chans/outputs [64wc,64wc+64).
//  - L1 channels permuted (R7-verified map, per 64-half): own D-frags, after
//    relu+cvt_pk in regs, ARE the L2 B-frags for global K-chunks {2wc,2wc+1}.
//  - The other two K-chunks come from the partner wave (wr,1-wc) via a 32KB
//    double-buffered LDS mailbox of B-frag register images (contiguous b128).
//  - b1 via k=9 ones-channel in xw; b2 via L2 MFMA C operand.
//  - 1 barrier/step. All accumulators f32x4 in VGPRs (<=170, lb(256,3)).

#define NN 256
#define MM 3
#define TT 4096
#define LL 4094
#define HH 128
#define CHUNKS 8
#define RPC 512
#define RPH 256
#define HALVES 2
#define STEPS 4
#define SR 64
#define XROW 24           // xw row stride in halfwords (48 B)

#define WS_W1 (1024 * 1024)            // after 1MB partials
#define WS_W2 (1024 * 1024 + 8192)     // w1t = 512 frags * 16B = 8KB

typedef __attribute__((ext_vector_type(8))) short bf16x8;
typedef __attribute__((ext_vector_type(4))) float f32x4;
typedef __attribute__((ext_vector_type(4))) unsigned int u32x4;
typedef __attribute__((ext_vector_type(2))) unsigned int u32x2;

__device__ __forceinline__ unsigned short f2bf(float x) {
    __hip_bfloat16 h = __float2bfloat16(x);
    union { __hip_bfloat16 h; unsigned short u; } v; v.h = h;
    return v.u;
}
__device__ __forceinline__ unsigned pkbf2(float a, float b) {
    union { __hip_bfloat162 h; unsigned u; } v;
    v.h = __float22bfloat162_rn(make_float2(a, b));   // v_cvt_pk_bf16_f32
    return v.u;
}

// ---------------------------------------------------------------------------
// Prep: fragment tables in d_ws.
// w1t[wc][cf][lane]: 16x16x32 A-frag; A-row m=lr holds channel
//   chan = 64wc + 32(cf>>1) + 8(lr>>2) + 4(cf&1) + (lr&3); k=8lq+e
//   (k<9: W1; k==9: b1 [pairs with xw's k=9 ones]; else 0).
//   This makes D-frag pair (2kkL,2kkL+1) == L2 B-frag of global kk=2wc+kkL.
// w2t[wc][of][kk][lane]: A-frag, o = 64wc+16of+lr, i = 32kk+8lq+e (kk global).
// ---------------------------------------------------------------------------
__global__ void pen_prep(const float* __restrict__ w1, const float* __restrict__ b1,
                         const float* __restrict__ w2,
                         unsigned short* __restrict__ w1t,
                         unsigned short* __restrict__ w2t)
{
    const int tid = threadIdx.x;
    for (int idx = tid; idx < 512; idx += 256) {
        const int wc = idx >> 8, cf = (idx >> 6) & 3, lane = idx & 63;
        const int lq = lane >> 4, lr = lane & 15;
        const int chan = 64 * wc + 32 * (cf >> 1) + 8 * (lr >> 2)
                       + 4 * (cf & 1) + (lr & 3);
        #pragma unroll
        for (int e = 0; e < 8; ++e) {
            const int k = 8 * lq + e;
            float v = 0.f;
            if (k < 9)       v = w1[k * HH + chan];
            else if (k == 9) v = b1[chan];
            w1t[idx * 8 + e] = f2bf(v);
        }
    }
    for (int idx = tid; idx < 2048; idx += 256) {
        const int lane = idx & 63;
        const int kk = (idx >> 6) & 3, of = (idx >> 8) & 3, wc = idx >> 10;
        const int lq = lane >> 4, lr = lane & 15;
        const int o = 64 * wc + 16 * of + lr;
        #pragma unroll
        for (int e = 0; e < 8; ++e) {
            const int i = 32 * kk + 8 * lq + e;
            w2t[idx * 8 + e] = f2bf(w2[i * HH + o]);
        }
    }
}

// ---------------------------------------------------------------------------
// Kernel A: block = (n, chunk of 512 rows); 2 halves of 256 rows, 4 steps each.
// ---------------------------------------------------------------------------
__global__ __launch_bounds__(256, 3) void pen_inner(
    const float* __restrict__ x,
    const float* __restrict__ b2,
    const unsigned short* __restrict__ w1t,
    const unsigned short* __restrict__ w2t,
    float* __restrict__ partials)
{
    __shared__ __align__(16) unsigned short xw[XROW * (RPH + 1) + 8];  // 12.3 KB
    __shared__ __align__(16) unsigned short mb[2][4][2][2][512];       // 32 KB
    __shared__ float red[2][HH];                                       // 1 KB

    const int tid  = threadIdx.x;
    const int wave = tid >> 6;
    const int lane = tid & 63;
    const int lr   = lane & 15;
    const int lq   = lane >> 4;
    const int wr   = wave >> 1;      // row-group owner
    const int wc   = wave & 1;       // channel/output half
    const int pw   = wave ^ 1;       // partner wave (same wr, other wc)

    const int bx    = blockIdx.x;
    const int n     = bx >> 3;
    const int chunk = bx & 7;

    const float* xn = x + n * (MM * TT);

    // ---- fragment tables -> registers ----
    bf16x8 w1f[4];
    #pragma unroll
    for (int cf = 0; cf < 4; ++cf)
        w1f[cf] = *(const bf16x8*)&w1t[((wc * 4 + cf) * 64 + lane) * 8];
    bf16x8 w2f[4][4];                       // [of][global kk]
    #pragma unroll
    for (int of = 0; of < 4; ++of)
        #pragma unroll
        for (int kk = 0; kk < 4; ++kk)
            w2f[of][kk] = *(const bf16x8*)&w2t[(((wc * 4 + of) * 4 + kk) * 64 + lane) * 8];
    f32x4 b2f[4];
    #pragma unroll
    for (int of = 0; of < 4; ++of)
        #pragma unroll
        for (int j = 0; j < 4; ++j)
            b2f[of][j] = b2[wc * 64 + of * 16 + lq * 4 + j];

    if (tid < XROW + 8) xw[XROW * RPH + tid] = 0;   // zero tail row (overread)

    const f32x4 zero4 = {0.f, 0.f, 0.f, 0.f};
    const int xo   = XROW * lr + 8 * lq;
    const int myk0 = 2 * wc;          // my global K-chunks {myk0, myk0+1}
    const int pk0  = 2 - 2 * wc;      // partner's global K-chunks

    float colsum[4][4] = {{0,0,0,0},{0,0,0,0},{0,0,0,0},{0,0,0,0}};

    for (int half = 0; half < HALVES; ++half) {
        const int lbase = chunk * RPC + half * RPH;

        // ---- stage 256 window-rows as bf16; k=9 = 1.0 (bias ones-channel) ----
        // Safe: all xw reads (phase-1) of the previous half precede its last
        // mid-step barrier, which every thread has passed before arriving here.
        {
            const int r = tid;                       // RPH == blockDim
            float kv[9];
            #pragma unroll
            for (int k = 0; k < 9; ++k) {            // k = i*3+m
                const int i = k / 3;
                const int m = k - i * 3;
                const int t = lbase + r + i;
                kv[k] = (t < TT) ? xn[m * TT + t] : 0.f;
            }
            u32x2 p0, p1, p2, z2;
            p0[0] = pkbf2(kv[0], kv[1]); p0[1] = pkbf2(kv[2], kv[3]);
            p1[0] = pkbf2(kv[4], kv[5]); p1[1] = pkbf2(kv[6], kv[7]);
            p2[0] = pkbf2(kv[8], 1.0f);  p2[1] = 0u;   // k=9 ones-channel
            z2[0] = 0u; z2[1] = 0u;
            *(u32x2*)&xw[XROW * r]      = p0;
            *(u32x2*)&xw[XROW * r + 4]  = p1;
            *(u32x2*)&xw[XROW * r + 8]  = p2;
            *(u32x2*)&xw[XROW * r + 12] = z2;
            *(u32x2*)&xw[XROW * r + 16] = z2;
            *(u32x2*)&xw[XROW * r + 20] = z2;
        }
        __syncthreads();   // staging visible

        for (int s = 0; s < STEPS; ++s) {
            const int buf = (half * STEPS + s) & 1;

            // ---- phase 1: L1 for own 32 rows x 64 chans; pack; mailbox ----
            bf16x8 pa[2][2];                 // [rf][kkL] own L2 B-frags
            #pragma unroll
            for (int rf = 0; rf < 2; ++rf) {
                const int R = s * SR + wr * 32 + rf * 16 + lr;
                const bf16x8 bfrag = *(const bf16x8*)&xw[R * XROW + 8 * lq];
                f32x4 a[4];
                #pragma unroll
                for (int cf = 0; cf < 4; ++cf)
                    a[cf] = __builtin_amdgcn_mfma_f32_16x16x32_bf16(
                                w1f[cf], bfrag, zero4, 0, 0, 0);
                #pragma unroll
                for (int kkL = 0; kkL < 2; ++kkL) {
                    u32x4 d;
                    d[0] = pkbf2(fmaxf(a[2*kkL][0], 0.f),   fmaxf(a[2*kkL][1], 0.f));
                    d[1] = pkbf2(fmaxf(a[2*kkL][2], 0.f),   fmaxf(a[2*kkL][3], 0.f));
                    d[2] = pkbf2(fmaxf(a[2*kkL+1][0], 0.f), fmaxf(a[2*kkL+1][1], 0.f));
                    d[3] = pkbf2(fmaxf(a[2*kkL+1][2], 0.f), fmaxf(a[2*kkL+1][3], 0.f));
                    pa[rf][kkL] = __builtin_bit_cast(bf16x8, d);
                    *(bf16x8*)&mb[buf][wave][kkL][rf][lane * 8] = pa[rf][kkL];
                }
            }
            __syncthreads();   // mailbox ready (dbuf covers WAR across steps)

            // ---- phase 2: L2 for own 32 rows x 64 outputs ----
            const bool tailw = (chunk == CHUNKS - 1) && (half == HALVES - 1)
                               && (s == STEPS - 1) && (wr == 1);  // wave-uniform
            #pragma unroll
            for (int rf = 0; rf < 2; ++rf) {
                const bf16x8 hp0 = *(const bf16x8*)&mb[buf][pw][0][rf][lane * 8];
                const bf16x8 hp1 = *(const bf16x8*)&mb[buf][pw][1][rf][lane * 8];
                f32x4 acc2[4];
                #pragma unroll
                for (int of = 0; of < 4; ++of)
                    acc2[of] = __builtin_amdgcn_mfma_f32_16x16x32_bf16(
                                   w2f[of][myk0], pa[rf][0], b2f[of], 0, 0, 0);
                #pragma unroll
                for (int of = 0; of < 4; ++of)
                    acc2[of] = __builtin_amdgcn_mfma_f32_16x16x32_bf16(
                                   w2f[of][myk0 + 1], pa[rf][1], acc2[of], 0, 0, 0);
                #pragma unroll
                for (int of = 0; of < 4; ++of)
                    acc2[of] = __builtin_amdgcn_mfma_f32_16x16x32_bf16(
                                   w2f[of][pk0], hp0, acc2[of], 0, 0, 0);
                #pragma unroll
                for (int of = 0; of < 4; ++of)
                    acc2[of] = __builtin_amdgcn_mfma_f32_16x16x32_bf16(
                                   w2f[of][pk0 + 1], hp1, acc2[of], 0, 0, 0);

                if (tailw && rf == 1) {          // rows 4080+lr; valid iff lr<14
                    const bool valid = lr < 14;
                    #pragma unroll
                    for (int of = 0; of < 4; ++of)
                        #pragma unroll
                        for (int j = 0; j < 4; ++j) {
                            float v = fmaxf(acc2[of][j], 0.f);
                            if (valid) colsum[of][j] += v;
                        }
                } else {
                    #pragma unroll
                    for (int of = 0; of < 4; ++of)
                        #pragma unroll
                        for (int j = 0; j < 4; ++j)
                            colsum[of][j] += fmaxf(acc2[of][j], 0.f);
                }
            }
        }
    }

    // ---- reduce over 16 row-lanes, cross-wr add via LDS, write partials ----
    #pragma unroll
    for (int of = 0; of < 4; ++of)
        #pragma unroll
        for (int j = 0; j < 4; ++j) {
            float v = colsum[of][j];
            #pragma unroll
            for (int msk = 1; msk < 16; msk <<= 1)
                v += __shfl_xor(v, msk, 64);
            if (lr == 0)
                red[wr][wc * 64 + of * 16 + lq * 4 + j] = v;
        }
    __syncthreads();
    if (tid < HH)
        partials[(n * CHUNKS + chunk) * HH + tid] = red[0][tid] + red[1][tid];
}

// ---------------------------------------------------------------------------
// Kernel B: tail in fp32. inner = sum partials; oi = inner@W3 + L*b3;
// io = [x[:, :, :2] flat (6), oi]; g = relu(io@rw1+rb1); out = g@rw2+rb2.
// ---------------------------------------------------------------------------
__global__ __launch_bounds__(128) void pen_outer(
    const float* __restrict__ x,
    const float* __restrict__ w3, const float* __restrict__ b3,
    const float* __restrict__ rw1, const float* __restrict__ rb1,
    const float* __restrict__ rw2, const float* __restrict__ rb2,
    const float* __restrict__ partials,
    float* __restrict__ out)
{
    __shared__ float S[HH];
    __shared__ float IO[136];
    __shared__ float G[HH];
    const int n = blockIdx.x;
    const int c = threadIdx.x;

    float s = 0.f;
    #pragma unroll
    for (int ch = 0; ch < CHUNKS; ++ch)
        s += partials[(n * CHUNKS + ch) * HH + c];
    S[c] = s;
    if (c < 6) IO[c] = x[n * (MM * TT) + (c >> 1) * TT + (c & 1)];
    __syncthreads();

    float oi = (float)LL * b3[c];
    for (int k = 0; k < HH; ++k) oi += S[k] * w3[k * HH + c];
    IO[6 + c] = oi;
    __syncthreads();

    float g = rb1[c];
    for (int k = 0; k < 134; ++k) g += IO[k] * rw1[k * HH + c];
    G[c] = fmaxf(g, 0.f);
    __syncthreads();

    if (c < 10) {
        float o = rb2[c];
        for (int k = 0; k < HH; ++k) o += G[k] * rw2[k * 10 + c];
        out[n * 10 + c] = o;
    }
}

// ---------------------------------------------------------------------------
extern "C" void kernel_launch(void* const* d_in, const int* in_sizes, int n_in,
                              void* d_out, int out_size, void* d_ws, size_t ws_size,
                              hipStream_t stream)
{
    (void)in_sizes; (void)n_in; (void)out_size; (void)ws_size;
    const float* x   = (const float*)d_in[0];
    const float* w1  = (const float*)d_in[1];
    const float* b1  = (const float*)d_in[2];
    const float* w2  = (const float*)d_in[3];
    const float* b2  = (const float*)d_in[4];
    const float* w3  = (const float*)d_in[5];
    const float* b3  = (const float*)d_in[6];
    const float* rw1 = (const float*)d_in[7];
    const float* rb1 = (const float*)d_in[8];
    const float* rw2 = (const float*)d_in[9];
    const float* rb2 = (const float*)d_in[10];

    float*          partials = (float*)d_ws;                       // 1 MB
    unsigned short* w1t = (unsigned short*)((char*)d_ws + WS_W1);  // 8 KB
    unsigned short* w2t = (unsigned short*)((char*)d_ws + WS_W2);  // 32 KB

    pen_prep<<<1, 256, 0, stream>>>(w1, b1, w2, w1t, w2t);
    pen_inner<<<NN * CHUNKS, 256, 0, stream>>>(x, b2, w1t, w2t, partials);
    pen_outer<<<NN, 128, 0, stream>>>(x, w3, b3, rw1, rb1, rw2, rb2, partials,
                                      (float*)d_out);
}